// Round 7
// baseline (1405.121 us; speedup 1.0000x reference)
//
#include <hip/hip_runtime.h>

#define D 64
#define BSHIFT 9              // 512 nodes per bucket
#define BNODES (1 << BSHIFT)
#define NBK_MAX 512           // supports N up to 262144

// ---------- bf16 helpers (bit-exact RNE pack, shift-based unpack) ----------
__device__ __forceinline__ unsigned int f2bf_rne(float f) {
    unsigned int b = __float_as_uint(f);
    return (b + 0x7fffu + ((b >> 16) & 1u)) >> 16;
}
__device__ __forceinline__ unsigned int pack_bf(float lo, float hi) {
    return f2bf_rne(lo) | (f2bf_rne(hi) << 16);
}
__device__ __forceinline__ float bflo(unsigned int u) { return __uint_as_float(u << 16); }
__device__ __forceinline__ float bfhi(unsigned int u) { return __uint_as_float(u & 0xffff0000u); }

// ---------- zero int region ----------
__global__ void zeroi_kernel(int* __restrict__ p, int n) {
    int i = blockIdx.x * blockDim.x + threadIdx.x;
    if (i < n) p[i] = 0;
}

// ---------- cast fp32 features -> packed bf16 (2 feats per uint) ----------
__global__ void cast_kernel(const float4* __restrict__ xin, uint2* __restrict__ xb, int n4) {
    int i = blockIdx.x * blockDim.x + threadIdx.x;
    int stride = gridDim.x * blockDim.x;
    for (; i < n4; i += stride) {
        float4 v = xin[i];
        uint2 o;
        o.x = pack_bf(v.x, v.y);
        o.y = pack_bf(v.z, v.w);
        xb[i] = o;
    }
}

// ---------- phase 1: per-(bucket,group) histogram. group = blockIdx&7 (~XCD) ----------
__global__ __launch_bounds__(256) void hist2_kernel(const int* __restrict__ dst,
                                                    int* __restrict__ cnt2,
                                                    int E, int NBK, int CE) {
    __shared__ int lh[NBK_MAX];
    for (int k = threadIdx.x; k < NBK; k += 256) lh[k] = 0;
    __syncthreads();
    int b = blockIdx.x, g = b & 7;
    int beg = b * CE, end = min(beg + CE, E);
    for (int e = beg + threadIdx.x; e < end; e += 256)
        atomicAdd(&lh[dst[e] >> BSHIFT], 1);
    __syncthreads();
    for (int k = threadIdx.x; k < NBK; k += 256)
        if (lh[k]) atomicAdd(&cnt2[(k << 3) | g], lh[k]);
}

// ---------- phase 2: exclusive scan of cnt2[NBK*8] -> cur2 + bstart ----------
__global__ __launch_bounds__(256) void scan2k_kernel(const int* __restrict__ cnt2,
                                                     int* __restrict__ cur2,
                                                     int* __restrict__ bstart, int NBK) {
    __shared__ int s[256];
    int n = NBK << 3;
    int tid = threadIdx.x;
    int base = tid * 8;
    int loc[8];
    int sum = 0;
    for (int j = 0; j < 8; ++j) {
        int idx = base + j;
        int v = (idx < n) ? cnt2[idx] : 0;
        loc[j] = sum;
        sum += v;
    }
    s[tid] = sum;
    __syncthreads();
    for (int off = 1; off < 256; off <<= 1) {
        int t = (tid >= off) ? s[tid - off] : 0;
        __syncthreads();
        s[tid] += t;
        __syncthreads();
    }
    int ebase = s[tid] - sum;
    for (int j = 0; j < 8; ++j) {
        int idx = base + j;
        if (idx < n) cur2[idx] = ebase + loc[j];
    }
    if (tid < NBK) bstart[tid] = ebase;
    if (tid == 0) bstart[NBK] = s[255];
}

// ---------- phase 3: scatter packed (src | dst_low<<17) records ----------
__global__ __launch_bounds__(256) void binscatter_kernel(
    const int* __restrict__ src, const int* __restrict__ dst,
    int* __restrict__ cur2, unsigned int* __restrict__ pairs,
    int E, int NBK, int CE) {
    __shared__ int lh[NBK_MAX];
    __shared__ int lbase[NBK_MAX];
    for (int k = threadIdx.x; k < NBK; k += 256) lh[k] = 0;
    __syncthreads();
    int b = blockIdx.x, g = b & 7;
    int beg = b * CE, end = min(beg + CE, E);
    for (int e = beg + threadIdx.x; e < end; e += 256)
        atomicAdd(&lh[dst[e] >> BSHIFT], 1);
    __syncthreads();
    for (int k = threadIdx.x; k < NBK; k += 256) {
        int c = lh[k];
        if (c) lbase[k] = atomicAdd(&cur2[(k << 3) | g], c);
        lh[k] = 0;
    }
    __syncthreads();
    for (int e = beg + threadIdx.x; e < end; e += 256) {
        int d = dst[e];
        int k = d >> BSHIFT;
        int r = atomicAdd(&lh[k], 1);
        pairs[lbase[k] + r] = (unsigned int)src[e] | ((unsigned int)(d & (BNODES - 1)) << 17);
    }
}

// ---------- phase 4: one workgroup per bucket -> rowptr + dst-sorted PACKED csr ----------
__global__ __launch_bounds__(256) void csr_build_kernel(
    const unsigned int* __restrict__ pairs, const int* __restrict__ bstart,
    int* __restrict__ rowptr, unsigned int* __restrict__ pcsr, int N, int NBK) {
    __shared__ int lcnt[BNODES];
    __shared__ int lofs[BNODES];
    __shared__ int s[256];
    int k = blockIdx.x;
    int tid = threadIdx.x;
    int node0 = k << BSHIFT;
    int nnodes = min(BNODES, N - node0);
    int rbeg = bstart[k], rend = bstart[k + 1];

    for (int j = tid; j < BNODES; j += 256) lcnt[j] = 0;
    __syncthreads();
    for (int i = rbeg + tid; i < rend; i += 256)
        atomicAdd(&lcnt[pairs[i] >> 17], 1);
    __syncthreads();
    int v0 = lcnt[2 * tid], v1 = lcnt[2 * tid + 1];
    int ps = v0 + v1;
    s[tid] = ps;
    __syncthreads();
    for (int off = 1; off < 256; off <<= 1) {
        int t = (tid >= off) ? s[tid - off] : 0;
        __syncthreads();
        s[tid] += t;
        __syncthreads();
    }
    int ebase = s[tid] - ps;
    lofs[2 * tid] = ebase;
    lofs[2 * tid + 1] = ebase + v0;
    __syncthreads();
    for (int j = tid; j < nnodes; j += 256) {
        int p = rbeg + lofs[j];
        rowptr[node0 + j] = p;
        lcnt[j] = p;
    }
    if (k == NBK - 1 && tid == 0) rowptr[N] = rend;
    __syncthreads();
    for (int i = rbeg + tid; i < rend; i += 256) {
        unsigned int rec = pairs[i];
        int j = rec >> 17;
        int pos = atomicAdd(&lcnt[j], 1);
        pcsr[pos] = rec;   // keep dlow bits for the fused kernel
    }
}

// ---------- fused layer: gather+mean (LDS atomics) + tiled GEMM, per 64-node tile ----------
// out[n][f] = relu?( sum_k Wl[f][k]*mean[n][k] + sum_k Wr[f][k]*feat[n][k] + b[f] )
#define WT_S 68    // Wt row stride (floats): 272B -> b128-aligned
#define AN_S 132   // An row stride (floats): 528B -> b128-aligned
__global__ __launch_bounds__(256) void fused_layer_kernel(
    const unsigned int* __restrict__ featb,      // bf16 features: gather + self source
    const int* __restrict__ rowptr, const unsigned int* __restrict__ pcsr,
    const float* __restrict__ Wl, const float* __restrict__ Wr,
    const float* __restrict__ bias,
    float* __restrict__ outf, unsigned int* __restrict__ outb, int N, int relu) {
    __shared__ float Wt[128 * WT_S];
    __shared__ float An[64 * AN_S];
    __shared__ float invdeg[64];
    int tid = threadIdx.x;

    // stage Wt (transposed weights), once per block
#pragma unroll
    for (int i = 0; i < 8; ++i) {
        int L = i * 256 + tid;
        int m = L >> 10;
        int r = L & 1023;
        int f = r >> 4;
        int kq = r & 15;
        const float* Wsrc = m ? Wr : Wl;
        float4 v = *(const float4*)(Wsrc + f * 64 + kq * 4);
        int kb = m * 64 + kq * 4;
        Wt[(kb + 0) * WT_S + f] = v.x;
        Wt[(kb + 1) * WT_S + f] = v.y;
        Wt[(kb + 2) * WT_S + f] = v.z;
        Wt[(kb + 3) * WT_S + f] = v.w;
    }

    int f0  = (tid & 15) * 4;   // output quad
    int nl0 = (tid >> 4) * 4;   // node quad (local)
    float4 bv = *(const float4*)(bias + f0);
    int hw = tid >> 5;          // half-wave id, 0..7
    int fl = tid & 31;          // feature-pair lane

    int numTiles = (N + 63) >> 6;
    for (int t = blockIdx.x; t < numTiles; t += gridDim.x) {
        int node0 = t << 6;
        int tbase = node0 & (BNODES - 1);   // tile base within its bucket
        __syncthreads();   // previous tile's GEMM reads complete
        // ---- stage self-features into An[.][64..128), zero mean-half An[.][0..64) ----
#pragma unroll
        for (int i = 0; i < 8; ++i) {
            int L = i * 256 + tid;
            int kq = L & 15;
            int h  = (L >> 4) & 1;
            int nl = L >> 5;
            int n = node0 + nl;
            float4 v = make_float4(0.f, 0.f, 0.f, 0.f);
            if (h && n < N) {
                uint2 u = *(const uint2*)(featb + n * 32 + kq * 2);
                v = make_float4(bflo(u.x), bfhi(u.x), bflo(u.y), bfhi(u.y));
            }
            *(float4*)&An[nl * AN_S + h * 64 + kq * 4] = v;
        }
        if (tid < 64) {
            int n = node0 + tid;
            float dg = 1.f;
            if (n < N) dg = (float)(rowptr[n + 1] - rowptr[n]);
            invdeg[tid] = 1.0f / fmaxf(dg, 1.0f);
        }
        __syncthreads();
        // ---- edge-parallel gather-accumulate (tile's edges are contiguous in pcsr) ----
        int ebeg = rowptr[node0];
        int eend = rowptr[min(node0 + 64, N)];
        int i = ebeg + hw;
        for (; i + 24 < eend; i += 32) {
            unsigned int r0 = pcsr[i], r1 = pcsr[i + 8], r2 = pcsr[i + 16], r3 = pcsr[i + 24];
            unsigned int u0 = featb[(r0 & 0x1FFFFu) * 32 + fl];
            unsigned int u1 = featb[(r1 & 0x1FFFFu) * 32 + fl];
            unsigned int u2 = featb[(r2 & 0x1FFFFu) * 32 + fl];
            unsigned int u3 = featb[(r3 & 0x1FFFFu) * 32 + fl];
            int n0 = (int)(r0 >> 17) - tbase;
            int n1 = (int)(r1 >> 17) - tbase;
            int n2 = (int)(r2 >> 17) - tbase;
            int n3 = (int)(r3 >> 17) - tbase;
            atomicAdd(&An[n0 * AN_S + 2 * fl],     bflo(u0));
            atomicAdd(&An[n0 * AN_S + 2 * fl + 1], bfhi(u0));
            atomicAdd(&An[n1 * AN_S + 2 * fl],     bflo(u1));
            atomicAdd(&An[n1 * AN_S + 2 * fl + 1], bfhi(u1));
            atomicAdd(&An[n2 * AN_S + 2 * fl],     bflo(u2));
            atomicAdd(&An[n2 * AN_S + 2 * fl + 1], bfhi(u2));
            atomicAdd(&An[n3 * AN_S + 2 * fl],     bflo(u3));
            atomicAdd(&An[n3 * AN_S + 2 * fl + 1], bfhi(u3));
        }
        for (; i < eend; i += 8) {
            unsigned int r0 = pcsr[i];
            unsigned int u0 = featb[(r0 & 0x1FFFFu) * 32 + fl];
            int n0 = (int)(r0 >> 17) - tbase;
            atomicAdd(&An[n0 * AN_S + 2 * fl],     bflo(u0));
            atomicAdd(&An[n0 * AN_S + 2 * fl + 1], bfhi(u0));
        }
        __syncthreads();
        // ---- scale mean-half by 1/deg ----
#pragma unroll
        for (int q = 0; q < 16; ++q) {
            int idx = q * 256 + tid;     // 4096 = 64 nodes x 64 k
            int nl = idx >> 6, k = idx & 63;
            An[nl * AN_S + k] *= invdeg[nl];
        }
        __syncthreads();
        // ---- GEMM: 4 nodes x 4 outputs per thread ----
        float acc00=0,acc01=0,acc02=0,acc03=0;
        float acc10=0,acc11=0,acc12=0,acc13=0;
        float acc20=0,acc21=0,acc22=0,acc23=0;
        float acc30=0,acc31=0,acc32=0,acc33=0;
#pragma unroll 4
        for (int k = 0; k < 128; ++k) {
            float4 w = *(const float4*)&Wt[k * WT_S + f0];
            float a0 = An[(nl0 + 0) * AN_S + k];
            float a1 = An[(nl0 + 1) * AN_S + k];
            float a2 = An[(nl0 + 2) * AN_S + k];
            float a3 = An[(nl0 + 3) * AN_S + k];
            acc00 += a0 * w.x; acc01 += a0 * w.y; acc02 += a0 * w.z; acc03 += a0 * w.w;
            acc10 += a1 * w.x; acc11 += a1 * w.y; acc12 += a1 * w.z; acc13 += a1 * w.w;
            acc20 += a2 * w.x; acc21 += a2 * w.y; acc22 += a2 * w.z; acc23 += a2 * w.w;
            acc30 += a3 * w.x; acc31 += a3 * w.y; acc32 += a3 * w.z; acc33 += a3 * w.w;
        }
        float r0[4] = {acc00+bv.x, acc01+bv.y, acc02+bv.z, acc03+bv.w};
        float r1[4] = {acc10+bv.x, acc11+bv.y, acc12+bv.z, acc13+bv.w};
        float r2[4] = {acc20+bv.x, acc21+bv.y, acc22+bv.z, acc23+bv.w};
        float r3[4] = {acc30+bv.x, acc31+bv.y, acc32+bv.z, acc33+bv.w};
        if (relu) {
#pragma unroll
            for (int q = 0; q < 4; ++q) {
                r0[q] = fmaxf(r0[q], 0.f); r1[q] = fmaxf(r1[q], 0.f);
                r2[q] = fmaxf(r2[q], 0.f); r3[q] = fmaxf(r3[q], 0.f);
            }
        }
        int nb = node0 + nl0;
        if (outf) {
            if (nb + 0 < N) *(float4*)(outf + (long long)(nb + 0) * D + f0) = make_float4(r0[0], r0[1], r0[2], r0[3]);
            if (nb + 1 < N) *(float4*)(outf + (long long)(nb + 1) * D + f0) = make_float4(r1[0], r1[1], r1[2], r1[3]);
            if (nb + 2 < N) *(float4*)(outf + (long long)(nb + 2) * D + f0) = make_float4(r2[0], r2[1], r2[2], r2[3]);
            if (nb + 3 < N) *(float4*)(outf + (long long)(nb + 3) * D + f0) = make_float4(r3[0], r3[1], r3[2], r3[3]);
        }
        if (outb) {
            int fo = f0 >> 1;
            if (nb + 0 < N) *(uint2*)(outb + (nb + 0) * 32 + fo) = make_uint2(pack_bf(r0[0], r0[1]), pack_bf(r0[2], r0[3]));
            if (nb + 1 < N) *(uint2*)(outb + (nb + 1) * 32 + fo) = make_uint2(pack_bf(r1[0], r1[1]), pack_bf(r1[2], r1[3]));
            if (nb + 2 < N) *(uint2*)(outb + (nb + 2) * 32 + fo) = make_uint2(pack_bf(r2[0], r2[1]), pack_bf(r2[2], r2[3]));
            if (nb + 3 < N) *(uint2*)(outb + (nb + 3) * 32 + fo) = make_uint2(pack_bf(r3[0], r3[1]), pack_bf(r3[2], r3[3]));
        }
    }
}

extern "C" void kernel_launch(void* const* d_in, const int* in_sizes, int n_in,
                              void* d_out, int out_size, void* d_ws, size_t ws_size,
                              hipStream_t stream) {
    const float* x   = (const float*)d_in[0];
    const int* ei    = (const int*)d_in[1];
    const float* W1l = (const float*)d_in[2];
    const float* W1r = (const float*)d_in[3];
    const float* b1  = (const float*)d_in[4];
    const float* W2l = (const float*)d_in[5];
    const float* W2r = (const float*)d_in[6];
    const float* b2  = (const float*)d_in[7];

    const int E = in_sizes[1] / 2;
    const int N = in_sizes[0] / D;     // requires N <= 131072 (17-bit packing)
    const int* src  = ei;
    const int* dstp = ei + E;
    const int NBK = (N + BNODES - 1) >> BSHIFT;
    const int G1 = 512;
    const int CE = (E + G1 - 1) / G1;

    char* ws = (char*)d_ws;
    size_t off = 0;
    auto alloc = [&](size_t bytes) { void* p = ws + off; off = (off + bytes + 255) & ~(size_t)255; return p; };
    int* cnt2           = (int*)alloc((size_t)(NBK * 8) * 4);
    int* cur2           = (int*)alloc((size_t)(NBK * 8) * 4);
    int* bstart         = (int*)alloc((size_t)(NBK + 1) * 4);
    int* rowptr         = (int*)alloc((size_t)(N + 1) * 4);
    unsigned int* pairs = (unsigned int*)alloc((size_t)E * 4);
    unsigned int* pcsr  = (unsigned int*)alloc((size_t)E * 4);
    unsigned int* xb    = (unsigned int*)alloc((size_t)N * 32 * 4);  // bf16 x
    unsigned int* hb    = (unsigned int*)alloc((size_t)N * 32 * 4);  // bf16 h

    float* out = (float*)d_out;

    // ---- cast features to bf16 ----
    cast_kernel<<<2048, 256, 0, stream>>>((const float4*)x, (uint2*)xb, N * 16);

    // ---- CSR build: bucket counting sort, dense writes, packed records ----
    zeroi_kernel<<<(NBK * 8 + 255) / 256, 256, 0, stream>>>(cnt2, NBK * 8);
    hist2_kernel<<<G1, 256, 0, stream>>>(dstp, cnt2, E, NBK, CE);
    scan2k_kernel<<<1, 256, 0, stream>>>(cnt2, cur2, bstart, NBK);
    binscatter_kernel<<<G1, 256, 0, stream>>>(src, dstp, cur2, pairs, E, NBK, CE);
    csr_build_kernel<<<NBK, 256, 0, stream>>>(pairs, bstart, rowptr, pcsr, N, NBK);

    // ---- layer 1: fused gather+mean+GEMM, emits bf16 h ----
    fused_layer_kernel<<<512, 256, 0, stream>>>(xb, rowptr, pcsr, W1l, W1r, b1, nullptr, hb, N, 1);

    // ---- layer 2: fused, emits fp32 out ----
    fused_layer_kernel<<<512, 256, 0, stream>>>(hb, rowptr, pcsr, W2l, W2r, b2, out, nullptr, N, 0);
}

// Round 8
// 298.425 us; speedup vs baseline: 4.7085x; 4.7085x over previous
//
#include <hip/hip_runtime.h>

#define D 64
#define BSHIFT 9              // 512 nodes per bucket
#define BNODES (1 << BSHIFT)
#define NBK_MAX 512           // supports N up to 262144

// ---------- bf16 helpers (bit-exact RNE pack, shift-based unpack) ----------
__device__ __forceinline__ unsigned int f2bf_rne(float f) {
    unsigned int b = __float_as_uint(f);
    return (b + 0x7fffu + ((b >> 16) & 1u)) >> 16;
}
__device__ __forceinline__ unsigned int pack_bf(float lo, float hi) {
    return f2bf_rne(lo) | (f2bf_rne(hi) << 16);
}
__device__ __forceinline__ float bflo(unsigned int u) { return __uint_as_float(u << 16); }
__device__ __forceinline__ float bfhi(unsigned int u) { return __uint_as_float(u & 0xffff0000u); }

// ---------- zero int region ----------
__global__ void zeroi_kernel(int* __restrict__ p, int n) {
    int i = blockIdx.x * blockDim.x + threadIdx.x;
    if (i < n) p[i] = 0;
}

// ---------- cast fp32 features -> packed bf16 (2 feats per uint) ----------
__global__ void cast_kernel(const float4* __restrict__ xin, uint2* __restrict__ xb, int n4) {
    int i = blockIdx.x * blockDim.x + threadIdx.x;
    int stride = gridDim.x * blockDim.x;
    for (; i < n4; i += stride) {
        float4 v = xin[i];
        uint2 o;
        o.x = pack_bf(v.x, v.y);
        o.y = pack_bf(v.z, v.w);
        xb[i] = o;
    }
}

// ---------- phase 1: per-(bucket,group) histogram. group = blockIdx&7 (~XCD) ----------
__global__ __launch_bounds__(256) void hist2_kernel(const int* __restrict__ dst,
                                                    int* __restrict__ cnt2,
                                                    int E, int NBK, int CE) {
    __shared__ int lh[NBK_MAX];
    for (int k = threadIdx.x; k < NBK; k += 256) lh[k] = 0;
    __syncthreads();
    int b = blockIdx.x, g = b & 7;
    int beg = b * CE, end = min(beg + CE, E);
    for (int e = beg + threadIdx.x; e < end; e += 256)
        atomicAdd(&lh[dst[e] >> BSHIFT], 1);
    __syncthreads();
    for (int k = threadIdx.x; k < NBK; k += 256)
        if (lh[k]) atomicAdd(&cnt2[(k << 3) | g], lh[k]);
}

// ---------- phase 2: exclusive scan of cnt2[NBK*8] -> cur2 + bstart ----------
__global__ __launch_bounds__(256) void scan2k_kernel(const int* __restrict__ cnt2,
                                                     int* __restrict__ cur2,
                                                     int* __restrict__ bstart, int NBK) {
    __shared__ int s[256];
    int n = NBK << 3;
    int tid = threadIdx.x;
    int base = tid * 8;
    int loc[8];
    int sum = 0;
    for (int j = 0; j < 8; ++j) {
        int idx = base + j;
        int v = (idx < n) ? cnt2[idx] : 0;
        loc[j] = sum;
        sum += v;
    }
    s[tid] = sum;
    __syncthreads();
    for (int off = 1; off < 256; off <<= 1) {
        int t = (tid >= off) ? s[tid - off] : 0;
        __syncthreads();
        s[tid] += t;
        __syncthreads();
    }
    int ebase = s[tid] - sum;
    for (int j = 0; j < 8; ++j) {
        int idx = base + j;
        if (idx < n) cur2[idx] = ebase + loc[j];
    }
    if (tid < NBK) bstart[tid] = ebase;
    if (tid == 0) bstart[NBK] = s[255];
}

// ---------- phase 3: scatter packed (src | dst_low<<17) records ----------
__global__ __launch_bounds__(256) void binscatter_kernel(
    const int* __restrict__ src, const int* __restrict__ dst,
    int* __restrict__ cur2, unsigned int* __restrict__ pairs,
    int E, int NBK, int CE) {
    __shared__ int lh[NBK_MAX];
    __shared__ int lbase[NBK_MAX];
    for (int k = threadIdx.x; k < NBK; k += 256) lh[k] = 0;
    __syncthreads();
    int b = blockIdx.x, g = b & 7;
    int beg = b * CE, end = min(beg + CE, E);
    for (int e = beg + threadIdx.x; e < end; e += 256)
        atomicAdd(&lh[dst[e] >> BSHIFT], 1);
    __syncthreads();
    for (int k = threadIdx.x; k < NBK; k += 256) {
        int c = lh[k];
        if (c) lbase[k] = atomicAdd(&cur2[(k << 3) | g], c);
        lh[k] = 0;
    }
    __syncthreads();
    for (int e = beg + threadIdx.x; e < end; e += 256) {
        int d = dst[e];
        int k = d >> BSHIFT;
        int r = atomicAdd(&lh[k], 1);
        pairs[lbase[k] + r] = (unsigned int)src[e] | ((unsigned int)(d & (BNODES - 1)) << 17);
    }
}

// ---------- phase 4: one workgroup per bucket -> rowptr + dst-sorted csr ----------
__global__ __launch_bounds__(256) void csr_build_kernel(
    const unsigned int* __restrict__ pairs, const int* __restrict__ bstart,
    int* __restrict__ rowptr, int* __restrict__ csr, int N, int NBK) {
    __shared__ int lcnt[BNODES];
    __shared__ int lofs[BNODES];
    __shared__ int s[256];
    int k = blockIdx.x;
    int tid = threadIdx.x;
    int node0 = k << BSHIFT;
    int nnodes = min(BNODES, N - node0);
    int rbeg = bstart[k], rend = bstart[k + 1];

    for (int j = tid; j < BNODES; j += 256) lcnt[j] = 0;
    __syncthreads();
    for (int i = rbeg + tid; i < rend; i += 256)
        atomicAdd(&lcnt[pairs[i] >> 17], 1);
    __syncthreads();
    int v0 = lcnt[2 * tid], v1 = lcnt[2 * tid + 1];
    int ps = v0 + v1;
    s[tid] = ps;
    __syncthreads();
    for (int off = 1; off < 256; off <<= 1) {
        int t = (tid >= off) ? s[tid - off] : 0;
        __syncthreads();
        s[tid] += t;
        __syncthreads();
    }
    int ebase = s[tid] - ps;
    lofs[2 * tid] = ebase;
    lofs[2 * tid + 1] = ebase + v0;
    __syncthreads();
    for (int j = tid; j < nnodes; j += 256) {
        int p = rbeg + lofs[j];
        rowptr[node0 + j] = p;
        lcnt[j] = p;
    }
    if (k == NBK - 1 && tid == 0) rowptr[N] = rend;
    __syncthreads();
    for (int i = rbeg + tid; i < rend; i += 256) {
        unsigned int rec = pairs[i];
        int j = rec >> 17;
        int pos = atomicAdd(&lcnt[j], 1);
        csr[pos] = (int)(rec & 0x1FFFFu);
    }
}

// ---------- aggregation, bf16: 4 nodes per wave; quarter-wave per node, uint2 loads ----------
__global__ __launch_bounds__(256) void agg_bf_kernel(
    const unsigned int* __restrict__ xb, const int* __restrict__ rowptr,
    const int* __restrict__ csr, unsigned int* __restrict__ meanb, int N) {
    int lane = threadIdx.x & 63;
    int q  = lane >> 4;         // which of the wave's 4 nodes
    int fl = lane & 15;         // uint-pair lane: covers uints 2fl, 2fl+1 (features 4fl..4fl+3)
    int wid = blockIdx.x * (blockDim.x >> 6) + (threadIdx.x >> 6);
    int nwaves = gridDim.x * (blockDim.x >> 6);
    int nquads = (N + 3) >> 2;

    for (int p = wid; p < nquads; p += nwaves) {
        int node = p * 4 + q;
        bool valid = node < N;
        int beg = 0, end = 0;
        if (valid) { beg = rowptr[node]; end = rowptr[node + 1]; }
        float s0 = 0.f, s1 = 0.f, s2 = 0.f, s3 = 0.f;
        int j = beg;
        for (; j + 4 <= end; j += 4) {
            int i0 = csr[j], i1 = csr[j + 1], i2 = csr[j + 2], i3 = csr[j + 3];
            uint2 u0 = *(const uint2*)(xb + i0 * 32 + fl * 2);
            uint2 u1 = *(const uint2*)(xb + i1 * 32 + fl * 2);
            uint2 u2 = *(const uint2*)(xb + i2 * 32 + fl * 2);
            uint2 u3 = *(const uint2*)(xb + i3 * 32 + fl * 2);
            s0 += bflo(u0.x) + bflo(u1.x) + bflo(u2.x) + bflo(u3.x);
            s1 += bfhi(u0.x) + bfhi(u1.x) + bfhi(u2.x) + bfhi(u3.x);
            s2 += bflo(u0.y) + bflo(u1.y) + bflo(u2.y) + bflo(u3.y);
            s3 += bfhi(u0.y) + bfhi(u1.y) + bfhi(u2.y) + bfhi(u3.y);
        }
        for (; j < end; ++j) {
            uint2 u = *(const uint2*)(xb + csr[j] * 32 + fl * 2);
            s0 += bflo(u.x);
            s1 += bfhi(u.x);
            s2 += bflo(u.y);
            s3 += bfhi(u.y);
        }
        if (valid) {
            float inv = 1.0f / fmaxf((float)(end - beg), 1.0f);
            uint2 o;
            o.x = pack_bf(s0 * inv, s1 * inv);
            o.y = pack_bf(s2 * inv, s3 * inv);
            *(uint2*)(meanb + node * 32 + fl * 2) = o;
        }
    }
}

// ---------- fused linear as LDS-tiled GEMM; An stored bf16-packed in LDS ----------
// out[n][f] = relu?( sum_k Wl[f][k]*mean[n][k] + sum_k Wr[f][k]*x[n][k] + b[f] )
// An_u[n][j]: j<32 = mean row uints, j>=32 = x row uints. For uint kp, fp32 k = 2kp,2kp+1
// and Wt rows = 2kp, 2kp+1 uniformly (Wt = [Wl k-major | Wr k-major]).
#define WT_S 68    // Wt row stride (floats): 272B -> b128-aligned
#define AU_S 68    // An_u row stride (uints): 272B -> 16B-aligned
__global__ __launch_bounds__(256) void lin_gemm_kernel(
    const unsigned int* __restrict__ meanb, const unsigned int* __restrict__ xb,
    const float* __restrict__ Wl, const float* __restrict__ Wr,
    const float* __restrict__ bias,
    float* __restrict__ outf, unsigned int* __restrict__ outb, int N, int relu) {
    __shared__ float Wt[128 * WT_S];            // 34816 B
    __shared__ unsigned int An_u[64 * AU_S];    // 17408 B  (total ~52 KB -> 3 blocks/CU)
    int tid = threadIdx.x;

    // stage Wt (transposed weights), once per block
#pragma unroll
    for (int i = 0; i < 8; ++i) {
        int L = i * 256 + tid;
        int m = L >> 10;
        int r = L & 1023;
        int f = r >> 4;
        int kq = r & 15;
        const float* Wsrc = m ? Wr : Wl;
        float4 v = *(const float4*)(Wsrc + f * 64 + kq * 4);
        int kb = m * 64 + kq * 4;
        Wt[(kb + 0) * WT_S + f] = v.x;
        Wt[(kb + 1) * WT_S + f] = v.y;
        Wt[(kb + 2) * WT_S + f] = v.z;
        Wt[(kb + 3) * WT_S + f] = v.w;
    }

    int f0  = (tid & 15) * 4;   // output quad
    int nl0 = (tid >> 4) * 4;   // node quad (local)
    float4 bv = *(const float4*)(bias + f0);

    int numTiles = (N + 63) >> 6;
    for (int t = blockIdx.x; t < numTiles; t += gridDim.x) {
        int node0 = t << 6;
        __syncthreads();
        // stage An_u raw: 64 nodes x 64 uints via uint4 copies (no unpack)
#pragma unroll
        for (int i = 0; i < 4; ++i) {
            int L = i * 256 + tid;       // 0..1023
            int nl = L >> 4;             // node local
            int qq = L & 15;             // uint4 index: <8 mean, >=8 x
            int n = node0 + nl;
            uint4 v = make_uint4(0u, 0u, 0u, 0u);
            if (n < N) {
                const unsigned int* row = (qq < 8 ? meanb : xb) + n * 32 + (qq & 7) * 4;
                v = *(const uint4*)row;
            }
            *(uint4*)&An_u[nl * AU_S + qq * 4] = v;
        }
        __syncthreads();
        // GEMM: 4 nodes x 4 outputs per thread; 2 fp32-k per LDS uint
        float acc00=0,acc01=0,acc02=0,acc03=0;
        float acc10=0,acc11=0,acc12=0,acc13=0;
        float acc20=0,acc21=0,acc22=0,acc23=0;
        float acc30=0,acc31=0,acc32=0,acc33=0;
#pragma unroll 4
        for (int kp = 0; kp < 64; ++kp) {
            float4 w0 = *(const float4*)&Wt[(2 * kp) * WT_S + f0];
            float4 w1 = *(const float4*)&Wt[(2 * kp + 1) * WT_S + f0];
            unsigned int a0 = An_u[(nl0 + 0) * AU_S + kp];
            unsigned int a1 = An_u[(nl0 + 1) * AU_S + kp];
            unsigned int a2 = An_u[(nl0 + 2) * AU_S + kp];
            unsigned int a3 = An_u[(nl0 + 3) * AU_S + kp];
            float a0l = bflo(a0), a0h = bfhi(a0);
            float a1l = bflo(a1), a1h = bfhi(a1);
            float a2l = bflo(a2), a2h = bfhi(a2);
            float a3l = bflo(a3), a3h = bfhi(a3);
            acc00 += a0l * w0.x + a0h * w1.x; acc01 += a0l * w0.y + a0h * w1.y;
            acc02 += a0l * w0.z + a0h * w1.z; acc03 += a0l * w0.w + a0h * w1.w;
            acc10 += a1l * w0.x + a1h * w1.x; acc11 += a1l * w0.y + a1h * w1.y;
            acc12 += a1l * w0.z + a1h * w1.z; acc13 += a1l * w0.w + a1h * w1.w;
            acc20 += a2l * w0.x + a2h * w1.x; acc21 += a2l * w0.y + a2h * w1.y;
            acc22 += a2l * w0.z + a2h * w1.z; acc23 += a2l * w0.w + a2h * w1.w;
            acc30 += a3l * w0.x + a3h * w1.x; acc31 += a3l * w0.y + a3h * w1.y;
            acc32 += a3l * w0.z + a3h * w1.z; acc33 += a3l * w0.w + a3h * w1.w;
        }
        float r0[4] = {acc00+bv.x, acc01+bv.y, acc02+bv.z, acc03+bv.w};
        float r1[4] = {acc10+bv.x, acc11+bv.y, acc12+bv.z, acc13+bv.w};
        float r2[4] = {acc20+bv.x, acc21+bv.y, acc22+bv.z, acc23+bv.w};
        float r3[4] = {acc30+bv.x, acc31+bv.y, acc32+bv.z, acc33+bv.w};
        if (relu) {
#pragma unroll
            for (int qk = 0; qk < 4; ++qk) {
                r0[qk] = fmaxf(r0[qk], 0.f); r1[qk] = fmaxf(r1[qk], 0.f);
                r2[qk] = fmaxf(r2[qk], 0.f); r3[qk] = fmaxf(r3[qk], 0.f);
            }
        }
        int nb = node0 + nl0;
        if (outf) {
            if (nb + 0 < N) *(float4*)(outf + (long long)(nb + 0) * D + f0) = make_float4(r0[0], r0[1], r0[2], r0[3]);
            if (nb + 1 < N) *(float4*)(outf + (long long)(nb + 1) * D + f0) = make_float4(r1[0], r1[1], r1[2], r1[3]);
            if (nb + 2 < N) *(float4*)(outf + (long long)(nb + 2) * D + f0) = make_float4(r2[0], r2[1], r2[2], r2[3]);
            if (nb + 3 < N) *(float4*)(outf + (long long)(nb + 3) * D + f0) = make_float4(r3[0], r3[1], r3[2], r3[3]);
        }
        if (outb) {
            int fo = f0 >> 1;
            if (nb + 0 < N) *(uint2*)(outb + (nb + 0) * 32 + fo) = make_uint2(pack_bf(r0[0], r0[1]), pack_bf(r0[2], r0[3]));
            if (nb + 1 < N) *(uint2*)(outb + (nb + 1) * 32 + fo) = make_uint2(pack_bf(r1[0], r1[1]), pack_bf(r1[2], r1[3]));
            if (nb + 2 < N) *(uint2*)(outb + (nb + 2) * 32 + fo) = make_uint2(pack_bf(r2[0], r2[1]), pack_bf(r2[2], r2[3]));
            if (nb + 3 < N) *(uint2*)(outb + (nb + 3) * 32 + fo) = make_uint2(pack_bf(r3[0], r3[1]), pack_bf(r3[2], r3[3]));
        }
    }
}

extern "C" void kernel_launch(void* const* d_in, const int* in_sizes, int n_in,
                              void* d_out, int out_size, void* d_ws, size_t ws_size,
                              hipStream_t stream) {
    const float* x   = (const float*)d_in[0];
    const int* ei    = (const int*)d_in[1];
    const float* W1l = (const float*)d_in[2];
    const float* W1r = (const float*)d_in[3];
    const float* b1  = (const float*)d_in[4];
    const float* W2l = (const float*)d_in[5];
    const float* W2r = (const float*)d_in[6];
    const float* b2  = (const float*)d_in[7];

    const int E = in_sizes[1] / 2;
    const int N = in_sizes[0] / D;     // requires N <= 131072 (17-bit packing)
    const int* src  = ei;
    const int* dstp = ei + E;
    const int NBK = (N + BNODES - 1) >> BSHIFT;
    const int G1 = 512;
    const int CE = (E + G1 - 1) / G1;

    char* ws = (char*)d_ws;
    size_t off = 0;
    auto alloc = [&](size_t bytes) { void* p = ws + off; off = (off + bytes + 255) & ~(size_t)255; return p; };
    int* cnt2           = (int*)alloc((size_t)(NBK * 8) * 4);
    int* cur2           = (int*)alloc((size_t)(NBK * 8) * 4);
    int* bstart         = (int*)alloc((size_t)(NBK + 1) * 4);
    int* rowptr         = (int*)alloc((size_t)(N + 1) * 4);
    unsigned int* pairs = (unsigned int*)alloc((size_t)E * 4);
    int* csr            = (int*)alloc((size_t)E * 4);
    unsigned int* xb    = (unsigned int*)alloc((size_t)N * 32 * 4);  // bf16 x
    unsigned int* meanb = (unsigned int*)alloc((size_t)N * 32 * 4);  // bf16 mean
    unsigned int* hb    = (unsigned int*)alloc((size_t)N * 32 * 4);  // bf16 h

    float* out = (float*)d_out;

    // ---- cast features to bf16 ----
    cast_kernel<<<2048, 256, 0, stream>>>((const float4*)x, (uint2*)xb, N * 16);

    // ---- CSR build: bucket counting sort, dense writes ----
    zeroi_kernel<<<(NBK * 8 + 255) / 256, 256, 0, stream>>>(cnt2, NBK * 8);
    hist2_kernel<<<G1, 256, 0, stream>>>(dstp, cnt2, E, NBK, CE);
    scan2k_kernel<<<1, 256, 0, stream>>>(cnt2, cur2, bstart, NBK);
    binscatter_kernel<<<G1, 256, 0, stream>>>(src, dstp, cur2, pairs, E, NBK, CE);
    csr_build_kernel<<<NBK, 256, 0, stream>>>(pairs, bstart, rowptr, csr, N, NBK);

    // ---- layer 1: gather bf16 x -> mean; GEMM emits bf16 h only ----
    agg_bf_kernel<<<4096, 256, 0, stream>>>(xb, rowptr, csr, meanb, N);
    lin_gemm_kernel<<<768, 256, 0, stream>>>(meanb, xb, W1l, W1r, b1, nullptr, hb, N, 1);

    // ---- layer 2: gather bf16 h -> mean; GEMM emits fp32 out ----
    agg_bf_kernel<<<4096, 256, 0, stream>>>(hb, rowptr, csr, meanb, N);
    lin_gemm_kernel<<<768, 256, 0, stream>>>(meanb, hb, W2l, W2r, b2, out, nullptr, N, 0);
}

// Round 9
// 271.305 us; speedup vs baseline: 5.1791x; 1.1000x over previous
//
#include <hip/hip_runtime.h>

#define D 64
#define BSHIFT 9              // 512 nodes per bucket
#define BNODES (1 << BSHIFT)
#define NBK_MAX 512           // supports N up to 262144

typedef __attribute__((ext_vector_type(8))) short bf16x8;
typedef __attribute__((ext_vector_type(4))) float f32x4;

// ---------- bf16 helpers (bit-exact RNE pack, shift-based unpack) ----------
__device__ __forceinline__ unsigned int f2bf_rne(float f) {
    unsigned int b = __float_as_uint(f);
    return (b + 0x7fffu + ((b >> 16) & 1u)) >> 16;
}
__device__ __forceinline__ unsigned int pack_bf(float lo, float hi) {
    return f2bf_rne(lo) | (f2bf_rne(hi) << 16);
}
__device__ __forceinline__ float bflo(unsigned int u) { return __uint_as_float(u << 16); }
__device__ __forceinline__ float bfhi(unsigned int u) { return __uint_as_float(u & 0xffff0000u); }

// ---------- zero int region ----------
__global__ void zeroi_kernel(int* __restrict__ p, int n) {
    int i = blockIdx.x * blockDim.x + threadIdx.x;
    if (i < n) p[i] = 0;
}

// ---------- cast fp32 features -> packed bf16 (2 feats per uint) ----------
__global__ void cast_kernel(const float4* __restrict__ xin, uint2* __restrict__ xb, int n4) {
    int i = blockIdx.x * blockDim.x + threadIdx.x;
    int stride = gridDim.x * blockDim.x;
    for (; i < n4; i += stride) {
        float4 v = xin[i];
        uint2 o;
        o.x = pack_bf(v.x, v.y);
        o.y = pack_bf(v.z, v.w);
        xb[i] = o;
    }
}

// ---------- phase 1: per-(bucket,group) histogram. group = blockIdx&7 (~XCD) ----------
__global__ __launch_bounds__(256) void hist2_kernel(const int* __restrict__ dst,
                                                    int* __restrict__ cnt2,
                                                    int E, int NBK, int CE) {
    __shared__ int lh[NBK_MAX];
    for (int k = threadIdx.x; k < NBK; k += 256) lh[k] = 0;
    __syncthreads();
    int b = blockIdx.x, g = b & 7;
    int beg = b * CE, end = min(beg + CE, E);
    for (int e = beg + threadIdx.x; e < end; e += 256)
        atomicAdd(&lh[dst[e] >> BSHIFT], 1);
    __syncthreads();
    for (int k = threadIdx.x; k < NBK; k += 256)
        if (lh[k]) atomicAdd(&cnt2[(k << 3) | g], lh[k]);
}

// ---------- phase 2: exclusive scan of cnt2[NBK*8] -> cur2 + bstart ----------
__global__ __launch_bounds__(256) void scan2k_kernel(const int* __restrict__ cnt2,
                                                     int* __restrict__ cur2,
                                                     int* __restrict__ bstart, int NBK) {
    __shared__ int s[256];
    int n = NBK << 3;
    int tid = threadIdx.x;
    int base = tid * 8;
    int loc[8];
    int sum = 0;
    for (int j = 0; j < 8; ++j) {
        int idx = base + j;
        int v = (idx < n) ? cnt2[idx] : 0;
        loc[j] = sum;
        sum += v;
    }
    s[tid] = sum;
    __syncthreads();
    for (int off = 1; off < 256; off <<= 1) {
        int t = (tid >= off) ? s[tid - off] : 0;
        __syncthreads();
        s[tid] += t;
        __syncthreads();
    }
    int ebase = s[tid] - sum;
    for (int j = 0; j < 8; ++j) {
        int idx = base + j;
        if (idx < n) cur2[idx] = ebase + loc[j];
    }
    if (tid < NBK) bstart[tid] = ebase;
    if (tid == 0) bstart[NBK] = s[255];
}

// ---------- phase 3: scatter packed (src | dst_low<<17) records ----------
__global__ __launch_bounds__(256) void binscatter_kernel(
    const int* __restrict__ src, const int* __restrict__ dst,
    int* __restrict__ cur2, unsigned int* __restrict__ pairs,
    int E, int NBK, int CE) {
    __shared__ int lh[NBK_MAX];
    __shared__ int lbase[NBK_MAX];
    for (int k = threadIdx.x; k < NBK; k += 256) lh[k] = 0;
    __syncthreads();
    int b = blockIdx.x, g = b & 7;
    int beg = b * CE, end = min(beg + CE, E);
    for (int e = beg + threadIdx.x; e < end; e += 256)
        atomicAdd(&lh[dst[e] >> BSHIFT], 1);
    __syncthreads();
    for (int k = threadIdx.x; k < NBK; k += 256) {
        int c = lh[k];
        if (c) lbase[k] = atomicAdd(&cur2[(k << 3) | g], c);
        lh[k] = 0;
    }
    __syncthreads();
    for (int e = beg + threadIdx.x; e < end; e += 256) {
        int d = dst[e];
        int k = d >> BSHIFT;
        int r = atomicAdd(&lh[k], 1);
        pairs[lbase[k] + r] = (unsigned int)src[e] | ((unsigned int)(d & (BNODES - 1)) << 17);
    }
}

// ---------- phase 4: one workgroup per bucket -> rowptr + dst-sorted csr ----------
__global__ __launch_bounds__(256) void csr_build_kernel(
    const unsigned int* __restrict__ pairs, const int* __restrict__ bstart,
    int* __restrict__ rowptr, int* __restrict__ csr, int N, int NBK) {
    __shared__ int lcnt[BNODES];
    __shared__ int lofs[BNODES];
    __shared__ int s[256];
    int k = blockIdx.x;
    int tid = threadIdx.x;
    int node0 = k << BSHIFT;
    int nnodes = min(BNODES, N - node0);
    int rbeg = bstart[k], rend = bstart[k + 1];

    for (int j = tid; j < BNODES; j += 256) lcnt[j] = 0;
    __syncthreads();
    for (int i = rbeg + tid; i < rend; i += 256)
        atomicAdd(&lcnt[pairs[i] >> 17], 1);
    __syncthreads();
    int v0 = lcnt[2 * tid], v1 = lcnt[2 * tid + 1];
    int ps = v0 + v1;
    s[tid] = ps;
    __syncthreads();
    for (int off = 1; off < 256; off <<= 1) {
        int t = (tid >= off) ? s[tid - off] : 0;
        __syncthreads();
        s[tid] += t;
        __syncthreads();
    }
    int ebase = s[tid] - ps;
    lofs[2 * tid] = ebase;
    lofs[2 * tid + 1] = ebase + v0;
    __syncthreads();
    for (int j = tid; j < nnodes; j += 256) {
        int p = rbeg + lofs[j];
        rowptr[node0 + j] = p;
        lcnt[j] = p;
    }
    if (k == NBK - 1 && tid == 0) rowptr[N] = rend;
    __syncthreads();
    for (int i = rbeg + tid; i < rend; i += 256) {
        unsigned int rec = pairs[i];
        int j = rec >> 17;
        int pos = atomicAdd(&lcnt[j], 1);
        csr[pos] = (int)(rec & 0x1FFFFu);
    }
}

// ---------- aggregation, bf16: 4 nodes per wave; quarter-wave per node, uint2 loads ----------
__global__ __launch_bounds__(256) void agg_bf_kernel(
    const unsigned int* __restrict__ xb, const int* __restrict__ rowptr,
    const int* __restrict__ csr, unsigned int* __restrict__ meanb, int N) {
    int lane = threadIdx.x & 63;
    int q  = lane >> 4;         // which of the wave's 4 nodes
    int fl = lane & 15;         // uint-pair lane
    int wid = blockIdx.x * (blockDim.x >> 6) + (threadIdx.x >> 6);
    int nwaves = gridDim.x * (blockDim.x >> 6);
    int nquads = (N + 3) >> 2;

    for (int p = wid; p < nquads; p += nwaves) {
        int node = p * 4 + q;
        bool valid = node < N;
        int beg = 0, end = 0;
        if (valid) { beg = rowptr[node]; end = rowptr[node + 1]; }
        float s0 = 0.f, s1 = 0.f, s2 = 0.f, s3 = 0.f;
        int j = beg;
        for (; j + 4 <= end; j += 4) {
            int i0 = csr[j], i1 = csr[j + 1], i2 = csr[j + 2], i3 = csr[j + 3];
            uint2 u0 = *(const uint2*)(xb + i0 * 32 + fl * 2);
            uint2 u1 = *(const uint2*)(xb + i1 * 32 + fl * 2);
            uint2 u2 = *(const uint2*)(xb + i2 * 32 + fl * 2);
            uint2 u3 = *(const uint2*)(xb + i3 * 32 + fl * 2);
            s0 += bflo(u0.x) + bflo(u1.x) + bflo(u2.x) + bflo(u3.x);
            s1 += bfhi(u0.x) + bfhi(u1.x) + bfhi(u2.x) + bfhi(u3.x);
            s2 += bflo(u0.y) + bflo(u1.y) + bflo(u2.y) + bflo(u3.y);
            s3 += bfhi(u0.y) + bfhi(u1.y) + bfhi(u2.y) + bfhi(u3.y);
        }
        for (; j < end; ++j) {
            uint2 u = *(const uint2*)(xb + csr[j] * 32 + fl * 2);
            s0 += bflo(u.x);
            s1 += bfhi(u.x);
            s2 += bflo(u.y);
            s3 += bfhi(u.y);
        }
        if (valid) {
            float inv = 1.0f / fmaxf((float)(end - beg), 1.0f);
            uint2 o;
            o.x = pack_bf(s0 * inv, s1 * inv);
            o.y = pack_bf(s2 * inv, s3 * inv);
            *(uint2*)(meanb + node * 32 + fl * 2) = o;
        }
    }
}

// ---------- linear via MFMA: out[f][node] tiles, D = W * A ----------
// A-operand (weights): A[m=f=lane&15][k=quad*8+j] = 8 consecutive fp32 of W row, split hi/lo bf16.
// B-operand (features): B[k=quad*8+j][n=node=lane&15] = one uint4 (16B) of the node's bf16 row.
// C/D: col=lane&15=node, row=quad*4+reg = f  -> float4 / uint2 epilogue stores.
// wave = one 16-output f-tile x 64 nodes; block = 4 waves = all 64 outputs for a 64-node tile.
__global__ __launch_bounds__(256) void lin_mfma_kernel(
    const unsigned int* __restrict__ meanb, const unsigned int* __restrict__ xin,
    const float* __restrict__ Wl, const float* __restrict__ Wr,
    const float* __restrict__ bias,
    float* __restrict__ outf, unsigned int* __restrict__ outb, int N, int relu) {
    int tid = threadIdx.x;
    int ft   = tid >> 6;        // wave id = f-tile 0..3
    int lane = tid & 63;
    int lm   = lane & 15;
    int quad = lane >> 4;

    // ---- build hi/lo weight frags for the 4 K-steps (held in VGPRs) ----
    int f_a = ft * 16 + lm;     // weight output row this lane holds in the A-frag
    bf16x8 wh[4], wlo[4];
#pragma unroll
    for (int s = 0; s < 4; ++s) {
        int k8 = s * 32 + quad * 8;               // first k of this lane's 8 elements
        const float* Wsrc = (k8 < 64) ? Wl : Wr;
        const float* p = Wsrc + f_a * 64 + (k8 & 63);
        float4 w0 = *(const float4*)p;
        float4 w1 = *(const float4*)(p + 4);
        float w[8] = {w0.x, w0.y, w0.z, w0.w, w1.x, w1.y, w1.z, w1.w};
        bf16x8 h, l;
#pragma unroll
        for (int j = 0; j < 8; ++j) {
            unsigned int hb = f2bf_rne(w[j]);
            float hf = __uint_as_float(hb << 16);
            unsigned int lb = f2bf_rne(w[j] - hf);
            h[j] = (short)hb;
            l[j] = (short)lb;
        }
        wh[s] = h;
        wlo[s] = l;
    }

    int node0 = blockIdx.x * 64;
    f32x4 acc[4];
#pragma unroll
    for (int nt = 0; nt < 4; ++nt) acc[nt] = (f32x4){0.f, 0.f, 0.f, 0.f};

#pragma unroll
    for (int nt = 0; nt < 4; ++nt) {
        int node = node0 + nt * 16 + lm;
        bool v = node < N;
        const unsigned int* mrow = meanb + (long long)node * 32;
        const unsigned int* xrow = xin   + (long long)node * 32;
#pragma unroll
        for (int s = 0; s < 4; ++s) {
            uint4 u = make_uint4(0u, 0u, 0u, 0u);
            if (v) {
                const unsigned int* srcrow = (s < 2) ? mrow : xrow;
                u = *(const uint4*)(srcrow + (s & 1) * 16 + quad * 4);
            }
            union { uint4 u4; bf16x8 v8; } cv;
            cv.u4 = u;
            acc[nt] = __builtin_amdgcn_mfma_f32_16x16x32_bf16(wh[s],  cv.v8, acc[nt], 0, 0, 0);
            acc[nt] = __builtin_amdgcn_mfma_f32_16x16x32_bf16(wlo[s], cv.v8, acc[nt], 0, 0, 0);
        }
    }

    // ---- epilogue ----
    int fb = ft * 16 + quad * 4;       // 4 consecutive outputs this lane owns
    float4 bv = *(const float4*)(bias + fb);
#pragma unroll
    for (int nt = 0; nt < 4; ++nt) {
        int node = node0 + nt * 16 + lm;
        if (node >= N) continue;
        float r0 = acc[nt][0] + bv.x;
        float r1 = acc[nt][1] + bv.y;
        float r2 = acc[nt][2] + bv.z;
        float r3 = acc[nt][3] + bv.w;
        if (relu) {
            r0 = fmaxf(r0, 0.f); r1 = fmaxf(r1, 0.f);
            r2 = fmaxf(r2, 0.f); r3 = fmaxf(r3, 0.f);
        }
        if (outf) *(float4*)(outf + (long long)node * D + fb) = make_float4(r0, r1, r2, r3);
        if (outb) *(uint2*)(outb + (long long)node * 32 + (fb >> 1)) =
                      make_uint2(pack_bf(r0, r1), pack_bf(r2, r3));
    }
}

extern "C" void kernel_launch(void* const* d_in, const int* in_sizes, int n_in,
                              void* d_out, int out_size, void* d_ws, size_t ws_size,
                              hipStream_t stream) {
    const float* x   = (const float*)d_in[0];
    const int* ei    = (const int*)d_in[1];
    const float* W1l = (const float*)d_in[2];
    const float* W1r = (const float*)d_in[3];
    const float* b1  = (const float*)d_in[4];
    const float* W2l = (const float*)d_in[5];
    const float* W2r = (const float*)d_in[6];
    const float* b2  = (const float*)d_in[7];

    const int E = in_sizes[1] / 2;
    const int N = in_sizes[0] / D;     // requires N <= 131072 (17-bit packing)
    const int* src  = ei;
    const int* dstp = ei + E;
    const int NBK = (N + BNODES - 1) >> BSHIFT;
    const int G1 = 512;
    const int CE = (E + G1 - 1) / G1;

    char* ws = (char*)d_ws;
    size_t off = 0;
    auto alloc = [&](size_t bytes) { void* p = ws + off; off = (off + bytes + 255) & ~(size_t)255; return p; };
    int* cnt2           = (int*)alloc((size_t)(NBK * 8) * 4);
    int* cur2           = (int*)alloc((size_t)(NBK * 8) * 4);
    int* bstart         = (int*)alloc((size_t)(NBK + 1) * 4);
    int* rowptr         = (int*)alloc((size_t)(N + 1) * 4);
    unsigned int* pairs = (unsigned int*)alloc((size_t)E * 4);
    int* csr            = (int*)alloc((size_t)E * 4);
    unsigned int* xb    = (unsigned int*)alloc((size_t)N * 32 * 4);  // bf16 x
    unsigned int* meanb = (unsigned int*)alloc((size_t)N * 32 * 4);  // bf16 mean
    unsigned int* hb    = (unsigned int*)alloc((size_t)N * 32 * 4);  // bf16 h

    float* out = (float*)d_out;

    // ---- cast features to bf16 ----
    cast_kernel<<<2048, 256, 0, stream>>>((const float4*)x, (uint2*)xb, N * 16);

    // ---- CSR build: bucket counting sort, dense writes ----
    zeroi_kernel<<<(NBK * 8 + 255) / 256, 256, 0, stream>>>(cnt2, NBK * 8);
    hist2_kernel<<<G1, 256, 0, stream>>>(dstp, cnt2, E, NBK, CE);
    scan2k_kernel<<<1, 256, 0, stream>>>(cnt2, cur2, bstart, NBK);
    binscatter_kernel<<<G1, 256, 0, stream>>>(src, dstp, cur2, pairs, E, NBK, CE);
    csr_build_kernel<<<NBK, 256, 0, stream>>>(pairs, bstart, rowptr, csr, N, NBK);

    const int linGrid = (N + 63) / 64;

    // ---- layer 1: gather bf16 x -> mean; MFMA linear emits bf16 h ----
    agg_bf_kernel<<<4096, 256, 0, stream>>>(xb, rowptr, csr, meanb, N);
    lin_mfma_kernel<<<linGrid, 256, 0, stream>>>(meanb, xb, W1l, W1r, b1, nullptr, hb, N, 1);

    // ---- layer 2: gather bf16 h -> mean; MFMA linear emits fp32 out ----
    agg_bf_kernel<<<4096, 256, 0, stream>>>(hb, rowptr, csr, meanb, N);
    lin_mfma_kernel<<<linGrid, 256, 0, stream>>>(meanb, hb, W2l, W2r, b2, out, nullptr, N, 0);
}